// Round 8
// baseline (562.376 us; speedup 1.0000x reference)
//
#include <hip/hip_runtime.h>
#include <hip/hip_bf16.h>
#include <hip/hip_cooperative_groups.h>

namespace cg = cooperative_groups;

// GraphNeuralAssociator: GCN(3 layers, fp32) + all-pairs edge MLP.
// v8: (a) whole GCN chain (rownorm, w2pack, 6 GEMM phases, Amat/Bmat) fused
// into ONE cooperative kernel (512 blocks x 256 thr, grid.sync between
// phases) — kills ~11 us/launch overhead x 7. (b) edge_mlp: revert per-slab
// barrier (neutral-neg); chunk barriers are now lgkmcnt(0)+raw s_barrier
// (no vmcnt(0) drain -> w2 prefetch survives chunk boundaries); ch loop
// fully unrolled (address constant-folding).

#define NN 512
#define FF 256
#define HH 512

typedef __attribute__((ext_vector_type(8))) short s8v;   // 8 x bf16 bits
typedef __attribute__((ext_vector_type(4))) float f4v;   // MFMA acc

__device__ __forceinline__ ushort f2bf(float f) {
  unsigned u = __float_as_uint(f);
  unsigned r = (u + 0x7fffu + ((u >> 16) & 1u)) >> 16;
  return (ushort)r;
}

// ---------------- device tile GEMM: 16x64 tile, BK=32 ----------------------
// C[tile] = [relu]( A@B + bias + add ); global->reg prefetch double-buffer.
__device__ void tile_gemm(bool relu, int m0, int n0, int K,
                          const float* __restrict__ A, int lda,
                          const float* __restrict__ B, int ldb,
                          const float* __restrict__ bias,
                          const float* __restrict__ add, int ldadd,
                          float* __restrict__ C, int ldc, int tid)
{
  __shared__ float As[32][18];  // [k][m]
  __shared__ float Bs[32][68];  // [k][n]
  float4 acc = {0.f, 0.f, 0.f, 0.f};
  const int ty = tid >> 4, tx = tid & 15;

  const int am = tid >> 4;      // A row 0..15
  const int ak = tid & 15;      // k float2 index
  const int bk = tid >> 4;      // B rows bk, bk+16
  const int bn = tid & 15;      // col float4 index

  float2 pa = *(const float2*)&A[(m0 + am) * lda + ak * 2];
  float4 pb0 = *(const float4*)&B[bk * ldb + n0 + bn * 4];
  float4 pb1 = *(const float4*)&B[(bk + 16) * ldb + n0 + bn * 4];

  for (int k0 = 0; k0 < K; k0 += 32) {
    As[ak * 2][am] = pa.x;
    As[ak * 2 + 1][am] = pa.y;
    *(float4*)&Bs[bk][bn * 4] = pb0;
    *(float4*)&Bs[bk + 16][bn * 4] = pb1;
    __syncthreads();
    if (k0 + 32 < K) {  // next-chunk loads hide under FMAs
      pa = *(const float2*)&A[(m0 + am) * lda + k0 + 32 + ak * 2];
      pb0 = *(const float4*)&B[(k0 + 32 + bk) * ldb + n0 + bn * 4];
      pb1 = *(const float4*)&B[(k0 + 48 + bk) * ldb + n0 + bn * 4];
    }
#pragma unroll
    for (int k = 0; k < 32; ++k) {
      float a = As[k][ty];
      float4 b = *(const float4*)&Bs[k][tx * 4];
      acc.x += a * b.x; acc.y += a * b.y; acc.z += a * b.z; acc.w += a * b.w;
    }
    __syncthreads();
  }

  int m = m0 + ty;
  float4 v = acc;
  if (bias) {
    float4 bv = *(const float4*)&bias[n0 + tx * 4];
    v.x += bv.x; v.y += bv.y; v.z += bv.z; v.w += bv.w;
  }
  if (add) {
    float4 d = *(const float4*)&add[m * ldadd + n0 + tx * 4];
    v.x += d.x; v.y += d.y; v.z += d.z; v.w += d.w;
  }
  if (relu) {
    v.x = fmaxf(v.x, 0.f); v.y = fmaxf(v.y, 0.f);
    v.z = fmaxf(v.z, 0.f); v.w = fmaxf(v.w, 0.f);
  }
  *(float4*)&C[m * ldc + n0 + tx * 4] = v;
}

// ---------------- cooperative GCN mega-kernel ------------------------------
struct GP {
  const float *node, *adj, *w2;
  const float *g1wl, *g1bl, *g1ws, *g1bs;
  const float *g2wl, *g2bl, *g2ws, *g2bs;
  const float *g3wl, *g3bl, *g3ws, *g3bs;
  const float *w1, *b1;
  float *adjn, *Tb, *Sb, *xa, *xb, *emb, *Amat, *Bmat;
  ushort *w2t2;
};

__global__ __launch_bounds__(256)
void gcn_mega(GP p) {
  const int b = blockIdx.x;
  const int tid = threadIdx.x;
  cg::grid_group grid = cg::this_grid();

  // ---- phase 0: rownorm (all 512 blocks) + w2 pack (blocks 0..127)
  {
    const float* r = p.adj + b * NN;
    float a0 = r[tid], a1 = r[tid + 256];
    float s = a0 + a1;
#pragma unroll
    for (int m = 1; m < 64; m <<= 1) s += __shfl_xor(s, m);
    __shared__ float wsum[4];
    if ((tid & 63) == 0) wsum[tid >> 6] = s;
    __syncthreads();
    float inv = 1.f / (wsum[0] + wsum[1] + wsum[2] + wsum[3] + 1e-8f);
    float* o = p.adjn + b * NN;
    o[tid] = a0 * inv;
    o[tid + 256] = a1 * inv;
    if (b < 128) {
      int slab = b >> 3;
      int col = (b & 7) * 64 + (tid >> 2);
      int kq = tid & 3;
      int k0 = slab * 32 + kq * 8;
      ushort tmp[8];
#pragma unroll
      for (int e = 0; e < 8; ++e) tmp[e] = f2bf(p.w2[(k0 + e) * HH + col]);
      ushort* dst = p.w2t2 + slab * 16384 + col * 32 + kq * 8;
      *(ushort4*)dst = *(ushort4*)tmp;
      *(ushort4*)(dst + 4) = *(ushort4*)&tmp[4];
    }
  }
  grid.sync();

  // ---- phase 1: L1 T/S = node @ {g1wl,g1ws} + bias   (512 tiles, K=256)
  {
    int z = b >> 8, t = b & 255;
    int m0 = (t >> 3) * 16, n0 = (t & 7) * 64;
    tile_gemm(false, m0, n0, FF, p.node, FF, z ? p.g1ws : p.g1wl, HH,
              z ? p.g1bs : p.g1bl, nullptr, 0, z ? p.Sb : p.Tb, HH, tid);
  }
  grid.sync();

  // ---- phase 2: xa = relu(adjn @ Tb + Sb)   (256 tiles, K=512)
  if (b < 256) {
    int m0 = (b >> 3) * 16, n0 = (b & 7) * 64;
    tile_gemm(true, m0, n0, NN, p.adjn, NN, p.Tb, HH, nullptr, p.Sb, HH,
              p.xa, HH, tid);
  }
  grid.sync();

  // ---- phase 3: L2 T/S = xa @ {g2wl,g2ws} + bias   (512 tiles, K=512)
  {
    int z = b >> 8, t = b & 255;
    int m0 = (t >> 3) * 16, n0 = (t & 7) * 64;
    tile_gemm(false, m0, n0, HH, p.xa, HH, z ? p.g2ws : p.g2wl, HH,
              z ? p.g2bs : p.g2bl, nullptr, 0, z ? p.Sb : p.Tb, HH, tid);
  }
  grid.sync();

  // ---- phase 4: xb = relu(adjn @ Tb + Sb)   (256 tiles, K=512)
  if (b < 256) {
    int m0 = (b >> 3) * 16, n0 = (b & 7) * 64;
    tile_gemm(true, m0, n0, NN, p.adjn, NN, p.Tb, HH, nullptr, p.Sb, HH,
              p.xb, HH, tid);
  }
  grid.sync();

  // ---- phase 5: L3 T/S = xb @ {g3wl,g3ws} + bias   (256 tiles, K=512, N=256)
  if (b < 256) {
    int z = b >> 7, t = b & 127;
    int m0 = (t >> 2) * 16, n0 = (t & 3) * 64;
    tile_gemm(false, m0, n0, HH, p.xb, HH, z ? p.g3ws : p.g3wl, FF,
              z ? p.g3bs : p.g3bl, nullptr, 0, z ? p.Sb : p.Tb, FF, tid);
  }
  grid.sync();

  // ---- phase 6: emb = adjn @ Tb + Sb (no relu)   (128 tiles, K=512, N=256)
  if (b < 128) {
    int m0 = (b >> 2) * 16, n0 = (b & 3) * 64;
    tile_gemm(false, m0, n0, NN, p.adjn, NN, p.Tb, FF, nullptr, p.Sb, FF,
              p.emb, FF, tid);
  }
  grid.sync();

  // ---- phase 7: Amat = emb@w1_top + b1, Bmat = emb@w1_bot  (512 tiles, K=256)
  {
    int z = b >> 8, t = b & 255;
    int m0 = (t >> 3) * 16, n0 = (t & 7) * 64;
    tile_gemm(false, m0, n0, FF, p.emb, FF, z ? (p.w1 + FF * HH) : p.w1, HH,
              z ? nullptr : p.b1, nullptr, 0, z ? p.Bmat : p.Amat, HH, tid);
  }
}

// ---------------- fused edge MLP ----------------
// Block = 8 i's x 16 j's = 128 pairs x all 512 cols. 512 threads = 8 waves;
// wave w owns cols [64w, 64w+64): 8 mf x 4 nf fragments (128 acc regs).
// K=512 in 4 chunks of 128, double-buffered LDS (2 x 32 KB, XOR-swizzled).
// LDS padded to 84KB -> 1 block/CU -> 256-reg/thread budget (no spill).
// T14 async-STAGE split; T5 setprio; chunk barriers = lgkmcnt(0)+s_barrier
// (no vmcnt drain); ch loop fully unrolled.
__global__ __launch_bounds__(512)
__attribute__((amdgpu_waves_per_eu(2, 2)))
void edge_mlp(const float* __restrict__ Amat, const float* __restrict__ Bmat,
              const ushort* __restrict__ w2t2,
              const float* __restrict__ b2, const float* __restrict__ w3,
              const float* __restrict__ b3,
              float* __restrict__ edges)
{
  __shared__ ushort h1s[2][128 * 128];  // 64 KB
  __shared__ float part[8][640];        // 20 KB (only [8][128] used; pads LDS)

  // exact upper-triangle tile decode: tiles before col-block bj = bj^2+bj
  const int tb = (int)blockIdx.x;
  int bj = (int)((sqrtf(4.f * tb + 1.f) - 1.f) * 0.5f);
  while (bj * bj + bj > tb) --bj;
  while ((bj + 1) * (bj + 2) <= tb) ++bj;
  const int bi = tb - bj * bj - bj;

  const int tid = threadIdx.x;
  const int wid = tid >> 6;
  const int lane = tid & 63;
  const int l15 = lane & 15;
  const int lg = lane >> 4;

  const f4v zero = {0.f, 0.f, 0.f, 0.f};
  f4v acc[8][4];
#pragma unroll
  for (int mf = 0; mf < 8; ++mf)
#pragma unroll
    for (int nf = 0; nf < 4; ++nf) acc[mf][nf] = zero;

  // ---- staged registers (half = 4 q-iters = 32 VGPRs) ----
  float4 sa[4], sb[4];
  auto issue_half = [&](int ch, int h) {  // issue global loads only
#pragma unroll
    for (int q = 0; q < 4; ++q) {
      int fidx = (h * 4 + q) * 512 + tid;
      int p = fidx >> 5;        // pair row 0..127
      int k4 = fidx & 31;       // float4 index within 128-k chunk
      int i = bi * 8 + (p >> 4);
      int j = bj * 16 + (p & 15);
      sa[q] = *(const float4*)(Amat + i * HH + ch * 128 + k4 * 4);
      sb[q] = *(const float4*)(Bmat + j * HH + ch * 128 + k4 * 4);
    }
  };
  auto write_half = [&](int buf, int h) {  // cvt + LDS write (waits on loads)
#pragma unroll
    for (int q = 0; q < 4; ++q) {
      int fidx = (h * 4 + q) * 512 + tid;
      int p = fidx >> 5;
      int k4 = fidx & 31;
      ushort4 pk;
      pk.x = f2bf(fmaxf(sa[q].x + sb[q].x, 0.f));
      pk.y = f2bf(fmaxf(sa[q].y + sb[q].y, 0.f));
      pk.z = f2bf(fmaxf(sa[q].z + sb[q].z, 0.f));
      pk.w = f2bf(fmaxf(sa[q].w + sb[q].w, 0.f));
      int off = (p * 256 + k4 * 8) ^ ((p & 7) << 4);
      *(ushort4*)((char*)h1s[buf] + off) = pk;
    }
  };

  // prologue: stage chunk 0 into buf 0
  issue_half(0, 0); write_half(0, 0);
  issue_half(0, 1); write_half(0, 1);
  __syncthreads();

  // wave's w2 base: cols [64*wid ..), lane l15 col, lane-group lg k-offset
  const ushort* wbase = w2t2 + wid * 2048 + l15 * 32 + lg * 8;

  // rolling w2 prefetch (one 32-k slab ahead, across chunk boundaries)
  s8v nb0, nb1, nb2, nb3;
  nb0 = *(const s8v*)wbase;
  nb1 = *(const s8v*)(wbase + 512);
  nb2 = *(const s8v*)(wbase + 1024);
  nb3 = *(const s8v*)(wbase + 1536);

  // one 32-k slab: 8 ds_reads + 32 MFMAs, rolls w2 prefetch
  auto slab_step = [&](int cur, int slab) {
    s8v cb0 = nb0, cb1 = nb1, cb2 = nb2, cb3 = nb3;
    if (slab < 15) {
      const ushort* wb = wbase + (slab + 1) * 16384;
      nb0 = *(const s8v*)wb;
      nb1 = *(const s8v*)(wb + 512);
      nb2 = *(const s8v*)(wb + 1024);
      nb3 = *(const s8v*)(wb + 1536);
    }
    int ks = slab & 3;
    __builtin_amdgcn_s_setprio(1);
#pragma unroll
    for (int mf = 0; mf < 8; ++mf) {
      int p = mf * 16 + l15;
      int off = (p * 256 + ks * 64 + lg * 16) ^ ((p & 7) << 4);
      s8v a = *(const s8v*)((const char*)h1s[cur] + off);
      acc[mf][0] = __builtin_amdgcn_mfma_f32_16x16x32_bf16(a, cb0, acc[mf][0], 0, 0, 0);
      acc[mf][1] = __builtin_amdgcn_mfma_f32_16x16x32_bf16(a, cb1, acc[mf][1], 0, 0, 0);
      acc[mf][2] = __builtin_amdgcn_mfma_f32_16x16x32_bf16(a, cb2, acc[mf][2], 0, 0, 0);
      acc[mf][3] = __builtin_amdgcn_mfma_f32_16x16x32_bf16(a, cb3, acc[mf][3], 0, 0, 0);
    }
    __builtin_amdgcn_s_setprio(0);
  };

  // lgkm-only chunk barrier: ds ordering without vmcnt(0) drain
  auto chunk_barrier = [] {
    asm volatile("s_waitcnt lgkmcnt(0)" ::: "memory");
    __builtin_amdgcn_s_barrier();
  };

#pragma unroll
  for (int ch = 0; ch < 4; ++ch) {
    int cur = ch & 1;
    if (ch < 3) issue_half(ch + 1, 0);       // loads in flight under slabs 0-1
    slab_step(cur, ch * 4 + 0);
    slab_step(cur, ch * 4 + 1);
    if (ch < 3) {
      write_half(cur ^ 1, 0);                // counted vmcnt (w2 loads younger)
      issue_half(ch + 1, 1);                 // loads in flight under slabs 2-3
    }
    slab_step(cur, ch * 4 + 2);
    slab_step(cur, ch * 4 + 3);
    if (ch < 3) write_half(cur ^ 1, 1);
    chunk_barrier();
  }

  // epilogue: h2 = relu(acc+b2); partial = h2 . w3 over this wave's 64 cols
  float bb[4], ww[4];
#pragma unroll
  for (int nf = 0; nf < 4; ++nf) {
    int col = wid * 64 + nf * 16 + l15;
    bb[nf] = b2[col];
    ww[nf] = w3[col];
  }
#pragma unroll
  for (int mf = 0; mf < 8; ++mf) {
    float ps[4];
#pragma unroll
    for (int e = 0; e < 4; ++e) {
      ps[e] = fmaxf(acc[mf][0][e] + bb[0], 0.f) * ww[0] +
              fmaxf(acc[mf][1][e] + bb[1], 0.f) * ww[1] +
              fmaxf(acc[mf][2][e] + bb[2], 0.f) * ww[2] +
              fmaxf(acc[mf][3][e] + bb[3], 0.f) * ww[3];
    }
#pragma unroll
    for (int m = 1; m < 16; m <<= 1) {
#pragma unroll
      for (int e = 0; e < 4; ++e) ps[e] += __shfl_xor(ps[e], m);
    }
    if (l15 == 0) {
#pragma unroll
      for (int e = 0; e < 4; ++e)
        part[wid][mf * 16 + lg * 4 + e] = ps[e];
    }
  }
  __syncthreads();
  if (tid < 128) {
    float tot = b3[0];
#pragma unroll
    for (int w = 0; w < 8; ++w) tot += part[w][tid];
    float sg = 1.f / (1.f + expf(-tot));
    int i = bi * 8 + (tid >> 4);
    int j = bj * 16 + (tid & 15);
    if (i < j) {
      edges[i * NN + j] = sg;
      edges[j * NN + i] = sg;
    } else if (i == j) {
      edges[i * NN + i] = 0.f;
    }
  }
}

extern "C" void kernel_launch(void* const* d_in, const int* in_sizes, int n_in,
                              void* d_out, int out_size, void* d_ws, size_t ws_size,
                              hipStream_t stream) {
  const float* node = (const float*)d_in[0];
  const float* adj  = (const float*)d_in[1];
  const float* g1wl = (const float*)d_in[2];
  const float* g1bl = (const float*)d_in[3];
  const float* g1ws = (const float*)d_in[4];
  const float* g1bs = (const float*)d_in[5];
  const float* g2wl = (const float*)d_in[6];
  const float* g2bl = (const float*)d_in[7];
  const float* g2ws = (const float*)d_in[8];
  const float* g2bs = (const float*)d_in[9];
  const float* g3wl = (const float*)d_in[10];
  const float* g3bl = (const float*)d_in[11];
  const float* g3ws = (const float*)d_in[12];
  const float* g3bs = (const float*)d_in[13];
  const float* w1 = (const float*)d_in[14];
  const float* b1 = (const float*)d_in[15];
  const float* w2 = (const float*)d_in[16];
  const float* b2 = (const float*)d_in[17];
  const float* w3 = (const float*)d_in[18];
  const float* b3 = (const float*)d_in[19];

  float* out = (float*)d_out;
  float* emb = out;                 // [512][256]
  float* edges = out + NN * FF;     // [512][512]

  char* wsb = (char*)d_ws;
  float* adjn = (float*)wsb;                     // 1 MB
  float* Tb   = (float*)(wsb + (1u << 20));      // 1 MB
  float* Sb   = (float*)(wsb + (2u << 20));      // 1 MB
  float* xa   = (float*)(wsb + (3u << 20));      // 1 MB
  float* xb   = (float*)(wsb + (4u << 20));      // 1 MB
  ushort* w2t2 = (ushort*)(wsb + (5u << 20));    // 512 KB
  float* Amat = Tb;  // reused after GCN
  float* Bmat = Sb;

  GP P;
  P.node = node; P.adj = adj; P.w2 = w2;
  P.g1wl = g1wl; P.g1bl = g1bl; P.g1ws = g1ws; P.g1bs = g1bs;
  P.g2wl = g2wl; P.g2bl = g2bl; P.g2ws = g2ws; P.g2bs = g2bs;
  P.g3wl = g3wl; P.g3bl = g3bl; P.g3ws = g3ws; P.g3bs = g3bs;
  P.w1 = w1; P.b1 = b1;
  P.adjn = adjn; P.Tb = Tb; P.Sb = Sb; P.xa = xa; P.xb = xb;
  P.emb = emb; P.Amat = Amat; P.Bmat = Bmat; P.w2t2 = w2t2;

  void* args[] = {&P};
  hipLaunchCooperativeKernel((const void*)gcn_mega, dim3(512), dim3(256),
                             args, 0, stream);

  // ---- fused edge MLP: exact triangular grid (32^2 + 32 = 1056 tiles)
  edge_mlp<<<1056, 512, 0, stream>>>(Amat, Bmat, w2t2, b2, w3, b3, edges);
}

// Round 9
// 188.249 us; speedup vs baseline: 2.9874x; 2.9874x over previous
//
#include <hip/hip_runtime.h>
#include <hip/hip_bf16.h>

// GraphNeuralAssociator: GCN(3 layers, fp32) + all-pairs edge MLP.
// Edge MLP layer 1 factorized: h1(i,j) = relu(Amat[i] + Bmat[j]).
// Layer 2 (68.6 GF) = bf16 MFMA 16x16x32, fp32 accum; layer 3 + sigmoid fused.
// v9: (a) revert v8's cooperative GCN (grid.sync ~55us/sync on MI355X ->
// 466us); back to v7 separate launches. (b) edge_mlp: stage only the 24
// UNDERLYING ROWS (8 A + 16 B, 12KB/chunk dbuf) to LDS instead of 128
// pair-expanded rows from global (10x less stage VMEM; A-row was re-read
// 16x, B-row 8x from L2). h1 built LDS->VALU->LDS. One extra lgkm-only
// barrier per chunk.

#define NN 512
#define FF 256
#define HH 512

typedef __attribute__((ext_vector_type(8))) short s8v;   // 8 x bf16 bits
typedef __attribute__((ext_vector_type(4))) float f4v;   // MFMA acc

__device__ __forceinline__ ushort f2bf(float f) {
  unsigned u = __float_as_uint(f);
  unsigned r = (u + 0x7fffu + ((u >> 16) & 1u)) >> 16;
  return (ushort)r;
}

// ---------------- prep: rownorm (blocks 0..511) + w2 pack (512..639) --------
__global__ __launch_bounds__(256)
void prep_kernel(const float* __restrict__ adj, float* __restrict__ adjn,
                 const float* __restrict__ w2, ushort* __restrict__ w2t2) {
  int b = blockIdx.x;
  int tid = threadIdx.x;
  if (b < 512) {
    const float* r = adj + b * NN;
    float a0 = r[tid], a1 = r[tid + 256];
    float s = a0 + a1;
#pragma unroll
    for (int m = 1; m < 64; m <<= 1) s += __shfl_xor(s, m);
    __shared__ float wsum[4];
    if ((tid & 63) == 0) wsum[tid >> 6] = s;
    __syncthreads();
    float inv = 1.f / (wsum[0] + wsum[1] + wsum[2] + wsum[3] + 1e-8f);
    float* o = adjn + b * NN;
    o[tid] = a0 * inv;
    o[tid + 256] = a1 * inv;
  } else {
    // w2 -> bf16 pack: w2t2[(k>>5)*16384 + col*32 + (k&31)]
    int b2 = b - 512;                       // 0..127
    int slab = b2 >> 3;                     // 16 slabs of 32 k
    int col = (b2 & 7) * 64 + (tid >> 2);
    int kq = tid & 3;                       // 8-k sub-block
    int k0 = slab * 32 + kq * 8;
    ushort tmp[8];
#pragma unroll
    for (int e = 0; e < 8; ++e) tmp[e] = f2bf(w2[(k0 + e) * HH + col]);
    ushort* dst = w2t2 + slab * 16384 + col * 32 + kq * 8;
    *(ushort4*)dst = *(ushort4*)tmp;
    *(ushort4*)(dst + 4) = *(ushort4*)&tmp[4];
  }
}

// ---------------- fp32 GEMM, 16x64 tile, BK=32, dual-output via z ----------
// C = [relu]( A@B + bias + add ); global->reg prefetch double-buffer.
template <bool RELU>
__global__ __launch_bounds__(256)
void gemm_ts(int M, int N, int K,
             const float* __restrict__ A, int lda,
             const float* __restrict__ B0, const float* __restrict__ B1, int ldb,
             const float* __restrict__ bias0, const float* __restrict__ bias1,
             const float* __restrict__ add0, const float* __restrict__ add1, int ldadd,
             float* __restrict__ C0, float* __restrict__ C1, int ldc)
{
  const float* B = blockIdx.z ? B1 : B0;
  const float* bias = blockIdx.z ? bias1 : bias0;
  const float* add = blockIdx.z ? add1 : add0;
  float* C = blockIdx.z ? C1 : C0;
  const int n0 = blockIdx.x * 64;
  const int m0 = blockIdx.y * 16;
  const int tid = threadIdx.x;
  const int ty = tid >> 4, tx = tid & 15;

  __shared__ float As[32][18];  // [k][m]
  __shared__ float Bs[32][68];  // [k][n]
  float4 acc = {0.f, 0.f, 0.f, 0.f};

  const int am = tid >> 4;      // A row 0..15
  const int ak = tid & 15;      // k float2 index
  const int bk = tid >> 4;      // B rows bk, bk+16
  const int bn = tid & 15;      // col float4 index

  float2 pa = *(const float2*)&A[(m0 + am) * lda + ak * 2];
  float4 pb0 = *(const float4*)&B[bk * ldb + n0 + bn * 4];
  float4 pb1 = *(const float4*)&B[(bk + 16) * ldb + n0 + bn * 4];

  for (int k0 = 0; k0 < K; k0 += 32) {
    As[ak * 2][am] = pa.x;
    As[ak * 2 + 1][am] = pa.y;
    *(float4*)&Bs[bk][bn * 4] = pb0;
    *(float4*)&Bs[bk + 16][bn * 4] = pb1;
    __syncthreads();
    if (k0 + 32 < K) {  // next-chunk loads hide under FMAs
      pa = *(const float2*)&A[(m0 + am) * lda + k0 + 32 + ak * 2];
      pb0 = *(const float4*)&B[(k0 + 32 + bk) * ldb + n0 + bn * 4];
      pb1 = *(const float4*)&B[(k0 + 48 + bk) * ldb + n0 + bn * 4];
    }
#pragma unroll
    for (int k = 0; k < 32; ++k) {
      float a = As[k][ty];
      float4 b = *(const float4*)&Bs[k][tx * 4];
      acc.x += a * b.x; acc.y += a * b.y; acc.z += a * b.z; acc.w += a * b.w;
    }
    __syncthreads();
  }

  int m = m0 + ty;
  float4 v = acc;
  if (bias) {
    float4 bv = *(const float4*)&bias[n0 + tx * 4];
    v.x += bv.x; v.y += bv.y; v.z += bv.z; v.w += bv.w;
  }
  if (add) {
    float4 d = *(const float4*)&add[m * ldadd + n0 + tx * 4];
    v.x += d.x; v.y += d.y; v.z += d.z; v.w += d.w;
  }
  if (RELU) {
    v.x = fmaxf(v.x, 0.f); v.y = fmaxf(v.y, 0.f);
    v.z = fmaxf(v.z, 0.f); v.w = fmaxf(v.w, 0.f);
  }
  *(float4*)&C[m * ldc + n0 + tx * 4] = v;
}

// ---------------- fused edge MLP ----------------
// Block = 8 i's x 16 j's = 128 pairs x all 512 cols. 512 threads = 8 waves;
// wave w owns cols [64w, 64w+64): 8 mf x 4 nf fragments (128 acc regs).
// K=512 in 4 chunks of 128. h1 double-buffered in LDS (2 x 32 KB, swizzled);
// the 24 source ROWS (8 A + 16 B) staged per chunk to LDS (2 x 12 KB) via
// T14 issue-early/write-late; h1 built LDS->VALU->LDS (stage VMEM 10x down).
// LDS 92 KB -> 1 block/CU -> 256-reg budget (no spill). T5 setprio on MFMAs.
__global__ __launch_bounds__(512)
__attribute__((amdgpu_waves_per_eu(2, 2)))
void edge_mlp(const float* __restrict__ Amat, const float* __restrict__ Bmat,
              const ushort* __restrict__ w2t2,
              const float* __restrict__ b2, const float* __restrict__ w3,
              const float* __restrict__ b3,
              float* __restrict__ edges)
{
  __shared__ ushort h1s[2][128 * 128];   // 64 KB
  __shared__ float rowsv[2][24][128];    // 24 KB: rows 0-7 = A, 8-23 = B
  __shared__ float part[8][128];         // 4 KB

  // exact upper-triangle tile decode: tiles before col-block bj = bj^2+bj
  const int tb = (int)blockIdx.x;
  int bj = (int)((sqrtf(4.f * tb + 1.f) - 1.f) * 0.5f);
  while (bj * bj + bj > tb) --bj;
  while ((bj + 1) * (bj + 2) <= tb) ++bj;
  const int bi = tb - bj * bj - bj;

  const int tid = threadIdx.x;
  const int wid = tid >> 6;
  const int lane = tid & 63;
  const int l15 = lane & 15;
  const int lg = lane >> 4;

  const f4v zero = {0.f, 0.f, 0.f, 0.f};
  f4v acc[8][4];
#pragma unroll
  for (int mf = 0; mf < 8; ++mf)
#pragma unroll
    for (int nf = 0; nf < 4; ++nf) acc[mf][nf] = zero;

  // ---- row staging: 24 rows x 128 floats per chunk = 768 float4 elems ----
  // elem e: row = e>>5 (A row if <8 else B row-8), kc = e&31 (float4 index).
  const int r1 = tid >> 5, kc1 = tid & 31;          // elem tid (all threads)
  const int r2 = 16 + (tid >> 5);                   // elem 512+tid (tid<256)
  const float* src1base = (r1 < 8) ? (Amat + (bi * 8 + r1) * HH)
                                   : (Bmat + (bj * 16 + r1 - 8) * HH);
  const float* src2base = Bmat + (bj * 16 + r2 - 8) * HH;  // rows 16..23

  float4 ra, rb;
  auto issue_rows = [&](int ch) {  // global loads only (tiny: 1.5 f4/thread)
    ra = *(const float4*)(src1base + ch * 128 + kc1 * 4);
    if (tid < 256) rb = *(const float4*)(src2base + ch * 128 + kc1 * 4);
  };
  auto write_rows = [&](int buf) {  // ds_write (waits on the row loads)
    *(float4*)&rowsv[buf][r1][kc1 * 4] = ra;
    if (tid < 256) *(float4*)&rowsv[buf][r2][kc1 * 4] = rb;
  };
  // build h1 chunk from staged rows: h1[p][k]=relu(Arow[i(p)]+Brow[j(p)]) bf16
  auto build_h1 = [&](int buf) {
#pragma unroll
    for (int q = 0; q < 8; ++q) {
      int fidx = q * 512 + tid;
      int p = fidx >> 5;        // pair row 0..127
      int k4 = fidx & 31;       // float4 index within 128-k chunk
      float4 av = *(const float4*)&rowsv[buf][p >> 4][k4 * 4];
      float4 bv = *(const float4*)&rowsv[buf][8 + (p & 15)][k4 * 4];
      ushort4 pk;
      pk.x = f2bf(fmaxf(av.x + bv.x, 0.f));
      pk.y = f2bf(fmaxf(av.y + bv.y, 0.f));
      pk.z = f2bf(fmaxf(av.z + bv.z, 0.f));
      pk.w = f2bf(fmaxf(av.w + bv.w, 0.f));
      int off = (p * 256 + k4 * 8) ^ ((p & 7) << 4);
      *(ushort4*)((char*)h1s[buf] + off) = pk;
    }
  };

  // lgkm-only barrier (no vmcnt drain; w2/row prefetch stays in flight)
  auto lgkm_barrier = [] {
    asm volatile("s_waitcnt lgkmcnt(0)" ::: "memory");
    __builtin_amdgcn_s_barrier();
  };

  // prologue: stage rows(0) -> rowsv[0], build h1s[0]
  issue_rows(0);
  write_rows(0);
  lgkm_barrier();           // rows visible block-wide
  build_h1(0);
  lgkm_barrier();           // h1s[0] ready

  // wave's w2 base: cols [64*wid ..), lane l15 col, lane-group lg k-offset
  const ushort* wbase = w2t2 + wid * 2048 + l15 * 32 + lg * 8;

  // rolling w2 prefetch (one 32-k slab ahead, across chunk boundaries)
  s8v nb0, nb1, nb2, nb3;
  nb0 = *(const s8v*)wbase;
  nb1 = *(const s8v*)(wbase + 512);
  nb2 = *(const s8v*)(wbase + 1024);
  nb3 = *(const s8v*)(wbase + 1536);

  // one 32-k slab: 8 ds_reads + 32 MFMAs, rolls w2 prefetch
  auto slab_step = [&](int cur, int slab) {
    s8v cb0 = nb0, cb1 = nb1, cb2 = nb2, cb3 = nb3;
    if (slab < 15) {
      const ushort* wb = wbase + (slab + 1) * 16384;
      nb0 = *(const s8v*)wb;
      nb1 = *(const s8v*)(wb + 512);
      nb2 = *(const s8v*)(wb + 1024);
      nb3 = *(const s8v*)(wb + 1536);
    }
    int ks = slab & 3;
    __builtin_amdgcn_s_setprio(1);
#pragma unroll
    for (int mf = 0; mf < 8; ++mf) {
      int p = mf * 16 + l15;
      int off = (p * 256 + ks * 64 + lg * 16) ^ ((p & 7) << 4);
      s8v a = *(const s8v*)((const char*)h1s[cur] + off);
      acc[mf][0] = __builtin_amdgcn_mfma_f32_16x16x32_bf16(a, cb0, acc[mf][0], 0, 0, 0);
      acc[mf][1] = __builtin_amdgcn_mfma_f32_16x16x32_bf16(a, cb1, acc[mf][1], 0, 0, 0);
      acc[mf][2] = __builtin_amdgcn_mfma_f32_16x16x32_bf16(a, cb2, acc[mf][2], 0, 0, 0);
      acc[mf][3] = __builtin_amdgcn_mfma_f32_16x16x32_bf16(a, cb3, acc[mf][3], 0, 0, 0);
    }
    __builtin_amdgcn_s_setprio(0);
  };

#pragma unroll
  for (int ch = 0; ch < 4; ++ch) {
    int cur = ch & 1;
    if (ch < 3) issue_rows(ch + 1);          // row loads fly under slabs 0-1
    slab_step(cur, ch * 4 + 0);
    slab_step(cur, ch * 4 + 1);
    if (ch < 3) write_rows(cur ^ 1);         // counted vmcnt (w2 loads younger)
    slab_step(cur, ch * 4 + 2);
    if (ch < 3) lgkm_barrier();              // rows visible block-wide
    slab_step(cur, ch * 4 + 3);
    if (ch < 3) {
      build_h1(cur ^ 1);                     // LDS->VALU->LDS
      lgkm_barrier();                        // h1s[cur^1] ready
    }
  }

  // epilogue: h2 = relu(acc+b2); partial = h2 . w3 over this wave's 64 cols
  float bb[4], ww[4];
#pragma unroll
  for (int nf = 0; nf < 4; ++nf) {
    int col = wid * 64 + nf * 16 + l15;
    bb[nf] = b2[col];
    ww[nf] = w3[col];
  }
#pragma unroll
  for (int mf = 0; mf < 8; ++mf) {
    float ps[4];
#pragma unroll
    for (int e = 0; e < 4; ++e) {
      ps[e] = fmaxf(acc[mf][0][e] + bb[0], 0.f) * ww[0] +
              fmaxf(acc[mf][1][e] + bb[1], 0.f) * ww[1] +
              fmaxf(acc[mf][2][e] + bb[2], 0.f) * ww[2] +
              fmaxf(acc[mf][3][e] + bb[3], 0.f) * ww[3];
    }
#pragma unroll
    for (int m = 1; m < 16; m <<= 1) {
#pragma unroll
      for (int e = 0; e < 4; ++e) ps[e] += __shfl_xor(ps[e], m);
    }
    if (l15 == 0) {
#pragma unroll
      for (int e = 0; e < 4; ++e)
        part[wid][mf * 16 + lg * 4 + e] = ps[e];
    }
  }
  __syncthreads();
  if (tid < 128) {
    float tot = b3[0];
#pragma unroll
    for (int w = 0; w < 8; ++w) tot += part[w][tid];
    float sg = 1.f / (1.f + expf(-tot));
    int i = bi * 8 + (tid >> 4);
    int j = bj * 16 + (tid & 15);
    if (i < j) {
      edges[i * NN + j] = sg;
      edges[j * NN + i] = sg;
    } else if (i == j) {
      edges[i * NN + i] = 0.f;
    }
  }
}

extern "C" void kernel_launch(void* const* d_in, const int* in_sizes, int n_in,
                              void* d_out, int out_size, void* d_ws, size_t ws_size,
                              hipStream_t stream) {
  const float* node = (const float*)d_in[0];
  const float* adj  = (const float*)d_in[1];
  const float* g1wl = (const float*)d_in[2];
  const float* g1bl = (const float*)d_in[3];
  const float* g1ws = (const float*)d_in[4];
  const float* g1bs = (const float*)d_in[5];
  const float* g2wl = (const float*)d_in[6];
  const float* g2bl = (const float*)d_in[7];
  const float* g2ws = (const float*)d_in[8];
  const float* g2bs = (const float*)d_in[9];
  const float* g3wl = (const float*)d_in[10];
  const float* g3bl = (const float*)d_in[11];
  const float* g3ws = (const float*)d_in[12];
  const float* g3bs = (const float*)d_in[13];
  const float* w1 = (const float*)d_in[14];
  const float* b1 = (const float*)d_in[15];
  const float* w2 = (const float*)d_in[16];
  const float* b2 = (const float*)d_in[17];
  const float* w3 = (const float*)d_in[18];
  const float* b3 = (const float*)d_in[19];

  float* out = (float*)d_out;
  float* emb = out;                 // [512][256]
  float* edges = out + NN * FF;     // [512][512]

  char* wsb = (char*)d_ws;
  float* adjn = (float*)wsb;                     // 1 MB
  float* Tb   = (float*)(wsb + (1u << 20));      // 1 MB
  float* Sb   = (float*)(wsb + (2u << 20));      // 1 MB
  float* xa   = (float*)(wsb + (3u << 20));      // 1 MB
  float* xb   = (float*)(wsb + (4u << 20));      // 1 MB
  ushort* w2t2 = (ushort*)(wsb + (5u << 20));    // 512 KB
  float* Amat = Tb;  // reused after GCN
  float* Bmat = Sb;

  // rownorm + w2 pack in one launch
  prep_kernel<<<640, 256, 0, stream>>>(adj, adjn, w2, w2t2);

  // ---- GCN layer 1: T=x@wl+bl, S=x@ws+bs ; xa=relu(adjn@T+S)
  gemm_ts<false><<<dim3(8, 32, 2), 256, 0, stream>>>(
      NN, HH, FF, node, FF, g1wl, g1ws, HH, g1bl, g1bs,
      nullptr, nullptr, 0, Tb, Sb, HH);
  gemm_ts<true><<<dim3(8, 32, 1), 256, 0, stream>>>(
      NN, HH, NN, adjn, NN, Tb, Tb, HH, nullptr, nullptr,
      Sb, Sb, HH, xa, xa, HH);
  // ---- GCN layer 2
  gemm_ts<false><<<dim3(8, 32, 2), 256, 0, stream>>>(
      NN, HH, HH, xa, HH, g2wl, g2ws, HH, g2bl, g2bs,
      nullptr, nullptr, 0, Tb, Sb, HH);
  gemm_ts<true><<<dim3(8, 32, 1), 256, 0, stream>>>(
      NN, HH, NN, adjn, NN, Tb, Tb, HH, nullptr, nullptr,
      Sb, Sb, HH, xb, xb, HH);
  // ---- GCN layer 3 (no relu) -> emb (d_out)
  gemm_ts<false><<<dim3(4, 32, 2), 256, 0, stream>>>(
      NN, FF, HH, xb, HH, g3wl, g3ws, FF, g3bl, g3bs,
      nullptr, nullptr, 0, Tb, Sb, FF);
  gemm_ts<false><<<dim3(4, 32, 1), 256, 0, stream>>>(
      NN, FF, NN, adjn, NN, Tb, Tb, FF, nullptr, nullptr,
      Sb, Sb, FF, emb, emb, FF);

  // ---- edge MLP layer-1 factorization: Amat = emb@w1_top+b1, Bmat = emb@w1_bot
  gemm_ts<false><<<dim3(8, 32, 2), 256, 0, stream>>>(
      NN, HH, FF, emb, FF, w1, w1 + FF * HH, HH, b1, nullptr,
      nullptr, nullptr, 0, Amat, Bmat, HH);

  // ---- fused edge MLP: exact triangular grid (32^2 + 32 = 1056 tiles)
  edge_mlp<<<1056, 512, 0, stream>>>(Amat, Bmat, w2t2, b2, w3, b3, edges);
}